// Round 3
// baseline (1041.038 us; speedup 1.0000x reference)
//
#include <hip/hip_runtime.h>
#include <hip/hip_bf16.h>

// FlyLoRALinear: out = (top8-mask(|x@A^T + d|) * (x@A^T)) @ B^T * 2
// x:[4,4096,4096]f32  A:[32,4096]f32  B:[4096,32]f32  d:[32]f32  out:[4,4096,4096]f32
#define IN_F   4096
#define RDIM   32
#define KSEL   8
#define OUT_F  4096
#define TOK    8        // tokens per WG
#define CHUNK  512      // k-elements staged per chunk
#define NCHUNK (IN_F / CHUNK)   // 8

typedef float  f4  __attribute__((ext_vector_type(4)));
typedef short  s8  __attribute__((ext_vector_type(8)));   // bf16x8 MFMA frag
typedef float  cf4 __attribute__((ext_vector_type(4)));   // MFMA accum

__device__ inline short f2bf(float f) {
  __hip_bfloat16 h = __float2bfloat16(f);
  return *reinterpret_cast<short*>(&h);
}

// ---------------- k0: B fp32 -> bf16 (131072 elems, 8/thread) --------------
__global__ __launch_bounds__(256) void k0_convB(const float* __restrict__ B,
                                                short* __restrict__ Bb) {
  int idx = blockIdx.x * 256 + threadIdx.x;     // 0..16383
  const f4* p = (const f4*)(B + (size_t)idx * 8);
  f4 v0 = p[0], v1 = p[1];
  s8 o;
  o[0] = f2bf(v0.x); o[1] = f2bf(v0.y); o[2] = f2bf(v0.z); o[3] = f2bf(v0.w);
  o[4] = f2bf(v1.x); o[5] = f2bf(v1.y); o[6] = f2bf(v1.z); o[7] = f2bf(v1.w);
  *(s8*)(Bb + (size_t)idx * 8) = o;
}

// Stage one [8 tok][512 k] fp32 chunk (16 KB) via global_load_lds width-16.
// Dest = wave-uniform base + lane*16 (linear in tid)  ✓
__device__ inline void stage_chunk(const float* __restrict__ x, int m0, int kb,
                                   float* dst, int tid) {
  #pragma unroll
  for (int p = 0; p < 2; ++p) {
    const int off = (p * 512 + tid) * 16;          // byte offset, 0..16K
    const int t   = off >> 11;                     // 2048 B per token row
    const float* g = x + (size_t)(m0 + t) * IN_F + kb + ((off & 2047) >> 2);
    __builtin_amdgcn_global_load_lds(
        (const __attribute__((address_space(1))) void*)g,
        (__attribute__((address_space(3))) void*)(dst + (off >> 2)),
        16, 0, 0);
  }
}

__global__ __launch_bounds__(512, 8) void fused_flylora(
    const float* __restrict__ x, const float* __restrict__ A,
    const short* __restrict__ Bb, const float* __restrict__ dbias,
    float* __restrict__ out)
{
  __shared__ __align__(16) float xs[2][TOK * CHUNK];   // 32 KB dbuf x-stage
  __shared__ double sdata[TOK][RDIM];                  // 2 KB exact scores
  __shared__ double db[RDIM];                          // 256 B bias (fp64)
  __shared__ __align__(16) short Zl[16 * RDIM];        // 1 KB; rows 8..15 = 0

  const int tid  = threadIdx.x;      // 0..511
  const int lane = tid & 63;
  const int w    = tid >> 6;         // 0..7
  const int m0   = blockIdx.x * TOK;

  if (tid < RDIM)  db[tid] = (double)dbias[tid];
  if (tid >= 256)  Zl[tid] = 0;      // zero token rows 8..15 (MFMA padding)

  // ---------------- phase 1: y = x @ A^T (fp32 FMA, fp64 reduce) -----------
  stage_chunk(x, m0, 0, xs[0], tid);

  float acc[TOK][4];                 // wave w owns r = 4w..4w+3
  #pragma unroll
  for (int t = 0; t < TOK; ++t)
    #pragma unroll
    for (int j = 0; j < 4; ++j) acc[t][j] = 0.f;

  const float* Abase = A + (size_t)(4 * w) * IN_F;

  int cur = 0;
  for (int c = 0; c < NCHUNK; ++c) {
    __syncthreads();                 // chunk c landed (barrier drains vmcnt)
    if (c + 1 < NCHUNK)              // prefetch next chunk async into other buf
      stage_chunk(x, m0, (c + 1) * CHUNK, xs[cur ^ 1], tid);

    const float* xsc = xs[cur];
    const int kbase = c * CHUNK;
    #pragma unroll
    for (int i = 0; i < 2; ++i) {
      const int kk = 256 * i + 4 * lane;
      f4 av[4];
      #pragma unroll
      for (int j = 0; j < 4; ++j)
        av[j] = *(const f4*)(Abase + (size_t)j * IN_F + kbase + kk);
      #pragma unroll
      for (int t = 0; t < TOK; ++t) {
        f4 xv = *(const f4*)&xsc[t * CHUNK + kk];
        #pragma unroll
        for (int j = 0; j < 4; ++j) {
          acc[t][j] = fmaf(xv.x, av[j].x, acc[t][j]);
          acc[t][j] = fmaf(xv.y, av[j].y, acc[t][j]);
          acc[t][j] = fmaf(xv.z, av[j].z, acc[t][j]);
          acc[t][j] = fmaf(xv.w, av[j].w, acc[t][j]);
        }
      }
    }
    cur ^= 1;
  }

  // Cross-lane reduce: fp64 butterfly over 64 lanes per accumulator.
  // Register-only (no LDS scratch, no extra barriers). fp64 tree-sum of the
  // 64 fp32 partials is within ~1e-15 rel of exact -> same top-k selection
  // behavior as the previously-passing serial-fp64 scheme (XLA ref noise 1e-6).
  #pragma unroll
  for (int t = 0; t < TOK; ++t)
    #pragma unroll
    for (int j = 0; j < 4; ++j) {
      double s = (double)acc[t][j];
      s += __shfl_xor(s, 32, 64);
      s += __shfl_xor(s, 16, 64);
      s += __shfl_xor(s,  8, 64);
      s += __shfl_xor(s,  4, 64);
      s += __shfl_xor(s,  2, 64);
      s += __shfl_xor(s,  1, 64);
      if (lane == 0) sdata[t][4 * w + j] = s;
    }
  __syncthreads();

  // ---------------- phase 2: rank-based top-8 (== jax.lax.top_k) -----------
  if (tid < TOK * RDIM) {            // 256 threads = 256 (t,i) pairs
    int t = tid >> 5, i = tid & 31;
    double si = sdata[t][i];
    double bi = fabs(si + db[i]);
    int rank = 0;
    #pragma unroll
    for (int j = 0; j < RDIM; ++j) {
      double bj = fabs(sdata[t][j] + db[j]);   // bit-identical for j==i
      rank += (bj > bi) || (bj == bi && j < i);
    }
    float z = (rank < KSEL) ? (float)si * 2.0f : 0.0f;   // fold SCALE=2
    Zl[t * RDIM + i] = f2bf(z);
  }
  __syncthreads();

  // ---------------- phase 3: out = Z @ B^T via mfma_f32_16x16x32_bf16 ------
  // Swapped operands (round-2-verified): a = Bb rows (o-cols), b = Z tokens.
  // D: col = lane&15 = token (0..7 valid), row = 4q+reg = o-col
  //   -> d[0..3] = 4 consecutive o-cols for one token: single f4 store.
  {
    const int rr = lane & 15;
    const int q  = lane >> 4;
    const int nb = w * 512;                       // wave w: cols [512w,512w+512)
    s8 zb = *(const s8*)&Zl[rr * RDIM + q * 8];   // B-operand (token col = rr)
    const short* Bp = Bb + (size_t)(nb + rr) * RDIM + q * 8;
    float* op = out + (size_t)(m0 + rr) * OUT_F + nb + q * 4;

    #pragma unroll
    for (int tile = 0; tile < 32; ++tile) {
      s8 a = *(const s8*)(Bp + (size_t)tile * 16 * RDIM);
      cf4 d = {0.f, 0.f, 0.f, 0.f};
      d = __builtin_amdgcn_mfma_f32_16x16x32_bf16(a, zb, d, 0, 0, 0);
      if (rr < TOK)
        *(f4*)(op + tile * 16) = *(const f4*)&d;  // 16 B contiguous store
    }
  }
}

extern "C" void kernel_launch(void* const* d_in, const int* in_sizes, int n_in,
                              void* d_out, int out_size, void* d_ws, size_t ws_size,
                              hipStream_t stream) {
  const float* x     = (const float*)d_in[0];
  const float* A     = (const float*)d_in[1];
  const float* B     = (const float*)d_in[2];
  const float* dbias = (const float*)d_in[3];
  float* out = (float*)d_out;

  short* Bb = (short*)d_ws;                      // 4096*32 bf16 = 256 KB
  hipLaunchKernelGGL(k0_convB,      dim3(64),   dim3(256), 0, stream, B, Bb);
  hipLaunchKernelGGL(fused_flylora, dim3(2048), dim3(512), 0, stream,
                     x, A, Bb, dbias, out);
}